// Round 1
// baseline (320.503 us; speedup 1.0000x reference)
//
#include <hip/hip_runtime.h>
#include <hip/hip_fp16.h>
#include <math.h>

#define BN_EPS 1e-5f
#define CAP 128  // per-node neighbor capacity (max degree ~55 for E/N=16 uniform)

typedef __attribute__((ext_vector_type(8))) short short8;
typedef __attribute__((ext_vector_type(4))) float floatx4;

__device__ inline unsigned short f2bf(float f) {
    union { float f; unsigned u; } x; x.f = f;
    unsigned r = x.u + 0x7fff + ((x.u >> 16) & 1);
    return (unsigned short)(r >> 16);
}
__device__ inline float bf2f(unsigned short h) {
    union { float f; unsigned u; } x; x.u = ((unsigned)h) << 16; return x.f;
}

// inline BN finalize: given raw sums (sums[c], sums[128+c]), produce scale/shift
__device__ inline void bn_sc_sh(float sum, float sumsq, float g, float be, float invN,
                                float& sc, float& sh) {
    float mean = sum * invN;
    float var = sumsq * invN - mean * mean;
    sc = g * rsqrtf(var + BN_EPS);
    sh = be - mean * sc;
}

// ---------------- weight packing (bf16 hi+lo, MFMA B-fragment order) ----------------
__device__ inline void pack_one(int idx, const float* W1, const float* W2, const float* Wm,
                                unsigned short* p1, unsigned short* p2, unsigned short* pm) {
    const float* W;
    unsigned short* pack;
    int f, l = idx & 63, t, n, stride, ncols;
    if (idx < 2048) {
        W = W1; pack = p1; f = idx >> 6; t = f >> 3; n = (f & 7) * 16 + (l & 15);
        stride = 128; ncols = 128;
    } else if (idx < 4096) {
        W = W2; pack = p2; f = (idx - 2048) >> 6; t = f >> 3; n = (f & 7) * 16 + (l & 15);
        stride = 128; ncols = 128;
    } else {
        W = Wm; pack = pm; f = (idx - 4096) >> 6; t = f / 3; n = (f % 3) * 16 + (l & 15);
        stride = 40; ncols = 40;
    }
    int q = l >> 4;
    unsigned short* pp = pack + f * 1024 + l * 16;
#pragma unroll
    for (int j = 0; j < 8; ++j) {
        int k = t * 32 + q * 8 + j;
        float v = (n < ncols) ? W[k * stride + n] : 0.f;
        unsigned short hi = f2bf(v);
        float lo = v - bf2f(hi);
        pp[j] = hi;
        pp[8 + j] = f2bf(lo);
    }
}

// ---------------- pre: pack weights (blocks 0..18) + zero fillc/stats (blocks 19..) ----
// Replaces the separate hipMemsetAsync dispatch. Pack output consumed only by later
// dispatches; zero region (fillc|stats) consumed by fill/stats in later dispatches.
__global__ __launch_bounds__(256) void k_pre(const float* __restrict__ W1,
                                             const float* __restrict__ W2,
                                             const float* __restrict__ Wm,
                                             unsigned short* __restrict__ p1,
                                             unsigned short* __restrict__ p2,
                                             unsigned short* __restrict__ pm,
                                             int4* __restrict__ zdst, int nz4) {
    if (blockIdx.x < 19) {
        int idx = blockIdx.x * 256 + threadIdx.x;
        if (idx < 4864) pack_one(idx, W1, W2, Wm, p1, p2, pm);
        return;
    }
    int i = (blockIdx.x - 19) * 256 + threadIdx.x;
    if (i < nz4) zdst[i] = make_int4(0, 0, 0, 0);
}

// ---------------- row loader: 8 consecutive k values as f32 ----------------
__device__ inline void load_row8(const float* arow, int kbase, float av[8]) {
    float4 a0 = *(const float4*)(arow + kbase);
    float4 a1 = *(const float4*)(arow + kbase + 4);
    av[0] = a0.x; av[1] = a0.y; av[2] = a0.z; av[3] = a0.w;
    av[4] = a1.x; av[5] = a1.y; av[6] = a1.z; av[7] = a1.w;
}
__device__ inline void load_row8(const __half* arow, int kbase, float av[8]) {
    float4 raw = *(const float4*)(arow + kbase);  // 8 halfs, 16B aligned
    const __half2* h = (const __half2*)&raw;
#pragma unroll
    for (int i = 0; i < 4; ++i) {
        float2 f = __half22float2(h[i]);
        av[2 * i] = f.x;
        av[2 * i + 1] = f.y;
    }
}

// ---------------- MFMA GEMM body: Y16[Mx128] = fp16( f(A) @ W ) ----------------
// 32 output rows per wave (two 16-row fragments share each wh/wl weight stream):
// halves the per-wave 64KB packW L2 traffic vs the 16-row version (weight streaming
// was the GEMM bottleneck: ~200MB L2 vs ~2.4us of MFMA issue per CU).
// FUSE_BN: f = relu(bn(.)) with scale/shift computed inline from raw sums+g+be.
// NOTE: no dinv here anymore -- gather applies dinv on both src and dst side, which
// makes layer-1 GEMM independent of the edge fill (enables same-grid overlap).
template <typename T, bool FUSE_BN>
__device__ __forceinline__ void gemm_body(int bid, const T* __restrict__ A,
                                          const unsigned short* __restrict__ packW,
                                          const float* __restrict__ sums,
                                          const float* __restrict__ g,
                                          const float* __restrict__ be, float invN,
                                          __half* __restrict__ C16, int M) {
    int lane = threadIdx.x & 63;
    int wv = threadIdx.x >> 6;
    int m0 = (bid * 4 + wv) * 32;
    if (m0 >= M) return;  // wave-uniform
    int row = lane & 15, quad = lane >> 4;
    bool has2 = (m0 + 16 < M);  // second 16-row fragment valid (M%16==0)

    floatx4 acc0[8], acc1[8];
#pragma unroll
    for (int nt = 0; nt < 8; ++nt) {
        acc0[nt] = (floatx4){0.f, 0.f, 0.f, 0.f};
        acc1[nt] = (floatx4){0.f, 0.f, 0.f, 0.f};
    }

    const T* arow0 = A + (size_t)(m0 + row) * 128;
    const T* arow1 = A + (size_t)((has2 ? m0 + 16 : m0) + row) * 128;
#pragma unroll
    for (int t = 0; t < 4; ++t) {
        int kbase = t * 32 + quad * 8;
        float av0[8], av1[8];
        load_row8(arow0, kbase, av0);
        load_row8(arow1, kbase, av1);
        if (FUSE_BN) {
#pragma unroll
            for (int j = 0; j < 8; ++j) {
                int c = kbase + j;
                float sc, sh;
                bn_sc_sh(sums[c], sums[128 + c], g[c], be[c], invN, sc, sh);
                av0[j] = fmaxf(av0[j] * sc + sh, 0.f);
                av1[j] = fmaxf(av1[j] * sc + sh, 0.f);
            }
        }
        short8 ah0, al0, ah1, al1;
#pragma unroll
        for (int j = 0; j < 8; ++j) {
            unsigned short hi0 = f2bf(av0[j]);
            ah0[j] = (short)hi0;
            al0[j] = (short)f2bf(av0[j] - bf2f(hi0));
            unsigned short hi1 = f2bf(av1[j]);
            ah1[j] = (short)hi1;
            al1[j] = (short)f2bf(av1[j] - bf2f(hi1));
        }
        const unsigned short* wp = packW + (size_t)(t * 8) * 1024 + lane * 16;
#pragma unroll
        for (int nt = 0; nt < 8; ++nt) {
            short8 wh = *(const short8*)wp;
            short8 wl = *(const short8*)(wp + 8);
            wp += 1024;
            acc0[nt] = __builtin_amdgcn_mfma_f32_16x16x32_bf16(ah0, wh, acc0[nt], 0, 0, 0);
            acc0[nt] = __builtin_amdgcn_mfma_f32_16x16x32_bf16(al0, wh, acc0[nt], 0, 0, 0);
            acc0[nt] = __builtin_amdgcn_mfma_f32_16x16x32_bf16(ah0, wl, acc0[nt], 0, 0, 0);
            acc1[nt] = __builtin_amdgcn_mfma_f32_16x16x32_bf16(ah1, wh, acc1[nt], 0, 0, 0);
            acc1[nt] = __builtin_amdgcn_mfma_f32_16x16x32_bf16(al1, wh, acc1[nt], 0, 0, 0);
            acc1[nt] = __builtin_amdgcn_mfma_f32_16x16x32_bf16(ah1, wl, acc1[nt], 0, 0, 0);
        }
    }

    // C/D layout: col = lane&15 (row var), row = quad*4 + reg
#pragma unroll
    for (int nt = 0; nt < 8; ++nt) {
#pragma unroll
        for (int r = 0; r < 4; ++r) {
            C16[(size_t)(m0 + quad * 4 + r) * 128 + nt * 16 + row] =
                __float2half_rn(acc0[nt][r]);
        }
    }
    if (has2) {
#pragma unroll
        for (int nt = 0; nt < 8; ++nt) {
#pragma unroll
            for (int r = 0; r < 4; ++r) {
                C16[(size_t)(m0 + 16 + quad * 4 + r) * 128 + nt * 16 + row] =
                    __float2half_rn(acc1[nt][r]);
            }
        }
    }
}

// ---------------- XCD-sharded CSR fill body ----------------
// Block group g = b&7 scans all E edges, writes only nodes with (d&7)==g: each
// group's col16 lines accumulate in ~one XCD's L2 (perf heuristic only).
__device__ __forceinline__ void fill_body(int b, const int* __restrict__ src,
                                          const int* __restrict__ dst, int E,
                                          int* __restrict__ fillc,
                                          unsigned short* __restrict__ col16, int nfill) {
    int g = b & 7;
    int rank = b >> 3;
    int stride = (nfill >> 3) * 256;
    for (int e = rank * 256 + threadIdx.x; e < E; e += stride) {
        int d = dst[e];
        if ((d & 7) != g) continue;
        int r = atomicAdd(&fillc[d], 1);
        if (r < CAP) col16[(size_t)d * CAP + r] = (unsigned short)src[e];
    }
}

// ---------------- merged: layer-1 GEMM (blocks 0..ngemm-1) + fill (rest) ----------------
// Independent work co-scheduled in one grid: MFMA/L2-bound gemm blocks overlap the
// latency/atomic-bound fill blocks (fill alone was 43us at 4% VALU, 16% HBM).
// GEMM blocks first so they occupy CUs immediately; fill blocks backfill remaining slots.
__global__ __launch_bounds__(256) void k_fill_gemm1(const float* __restrict__ x,
                                                    const unsigned short* __restrict__ packW1,
                                                    __half* __restrict__ y16, int M, int ngemm,
                                                    const int* __restrict__ src,
                                                    const int* __restrict__ dst, int E,
                                                    int* __restrict__ fillc,
                                                    unsigned short* __restrict__ col16,
                                                    int nfill) {
    if ((int)blockIdx.x < ngemm) {
        gemm_body<float, false>(blockIdx.x, x, packW1, nullptr, nullptr, nullptr, 0.f, y16, M);
        return;
    }
    fill_body((int)blockIdx.x - ngemm, src, dst, E, fillc, col16, nfill);
}

// ---------------- standalone GEMM (layer 2) ----------------
template <typename T, bool FUSE_BN>
__global__ __launch_bounds__(256) void k_gemm(const T* __restrict__ A,
                                              const unsigned short* __restrict__ packW,
                                              const float* __restrict__ sums,
                                              const float* __restrict__ g,
                                              const float* __restrict__ be, float invN,
                                              __half* __restrict__ C16, int M) {
    gemm_body<T, FUSE_BN>(blockIdx.x, A, packW, sums, g, be, invN, C16, M);
}

// ---------------- GCN aggregation (padded CSR gather), 1 wave per node ----------------
// y16 holds un-normalized xw; this kernel applies BOTH dinv factors:
// out[n] = dn * ( dn*y[n] + sum_s dinv[s]*y[s] ) + b   with dn = rsqrt(1+deg[n]).
__global__ __launch_bounds__(256) void k_gather(const __half2* __restrict__ y16,
                                                const int* __restrict__ fillc,
                                                const unsigned short* __restrict__ col16,
                                                const float* __restrict__ bias,
                                                __half2* __restrict__ out, int N) {
    int wv = threadIdx.x >> 6;
    int lane = threadIdx.x & 63;
    int n = blockIdx.x * 4 + wv;
    if (n >= N) return;  // wave-uniform exit
    int degraw = fillc[n];
    float dn = rsqrtf(1.f + (float)degraw);
    float2 self = __half22float2(y16[(size_t)n * 64 + lane]);
    float2 acc;
    acc.x = dn * self.x;
    acc.y = dn * self.y;
    int deg = min(degraw, CAP);
    const unsigned short* cb = col16 + (size_t)n * CAP;
    for (int jb = 0; jb < deg; jb += 64) {
        int cnt = min(64, deg - jb);
        int idx = (lane < cnt) ? (int)cb[jb + lane] : 0;
        float dv = (lane < cnt) ? rsqrtf(1.f + (float)fillc[idx]) : 0.f;
        int jj = 0;
        for (; jj + 8 <= cnt; jj += 8) {
            int s0 = __shfl(idx, jj + 0, 64);
            int s1 = __shfl(idx, jj + 1, 64);
            int s2 = __shfl(idx, jj + 2, 64);
            int s3 = __shfl(idx, jj + 3, 64);
            int s4 = __shfl(idx, jj + 4, 64);
            int s5 = __shfl(idx, jj + 5, 64);
            int s6 = __shfl(idx, jj + 6, 64);
            int s7 = __shfl(idx, jj + 7, 64);
            float w0 = __shfl(dv, jj + 0, 64);
            float w1 = __shfl(dv, jj + 1, 64);
            float w2 = __shfl(dv, jj + 2, 64);
            float w3 = __shfl(dv, jj + 3, 64);
            float w4 = __shfl(dv, jj + 4, 64);
            float w5 = __shfl(dv, jj + 5, 64);
            float w6 = __shfl(dv, jj + 6, 64);
            float w7 = __shfl(dv, jj + 7, 64);
            float2 r0 = __half22float2(y16[(size_t)s0 * 64 + lane]);
            float2 r1 = __half22float2(y16[(size_t)s1 * 64 + lane]);
            float2 r2 = __half22float2(y16[(size_t)s2 * 64 + lane]);
            float2 r3 = __half22float2(y16[(size_t)s3 * 64 + lane]);
            float2 r4 = __half22float2(y16[(size_t)s4 * 64 + lane]);
            float2 r5 = __half22float2(y16[(size_t)s5 * 64 + lane]);
            float2 r6 = __half22float2(y16[(size_t)s6 * 64 + lane]);
            float2 r7 = __half22float2(y16[(size_t)s7 * 64 + lane]);
            acc.x += w0 * r0.x + w1 * r1.x + w2 * r2.x + w3 * r3.x +
                     w4 * r4.x + w5 * r5.x + w6 * r6.x + w7 * r7.x;
            acc.y += w0 * r0.y + w1 * r1.y + w2 * r2.y + w3 * r3.y +
                     w4 * r4.y + w5 * r5.y + w6 * r6.y + w7 * r7.y;
        }
        for (; jj < cnt; ++jj) {
            int s = __shfl(idx, jj, 64);
            float w = __shfl(dv, jj, 64);
            float2 r = __half22float2(y16[(size_t)s * 64 + lane]);
            acc.x += w * r.x;
            acc.y += w * r.y;
        }
    }
    float2 b = *(const float2*)&bias[lane << 1];
    float2 o;
    o.x = dn * acc.x + b.x;
    o.y = dn * acc.y + b.y;
    out[(size_t)n * 64 + lane] = __float22half2_rn(o);
}

// ---------------- BN stats over fp16 h: per-column sum & sumsq (raw sums out) ----------------
// TRANSFORM: apply relu(bn(.)) using sums2/g2/be2 before accumulating (for stats3).
template <bool TRANSFORM>
__global__ __launch_bounds__(256) void k_stats(const __half2* __restrict__ h, int N,
                                               const float* __restrict__ sums2,
                                               const float* __restrict__ g2,
                                               const float* __restrict__ be2, float invN,
                                               float* __restrict__ stats) {
    int cp = threadIdx.x & 63;   // column pair
    int rg = threadIdx.x >> 6;   // row group 0..3
    int rbeg = blockIdx.x * 256;
    int rend = min(rbeg + 256, N);
    float scx = 1.f, shx = 0.f, scy = 1.f, shy = 0.f;
    if (TRANSFORM) {
        int c = cp * 2;
        bn_sc_sh(sums2[c], sums2[128 + c], g2[c], be2[c], invN, scx, shx);
        bn_sc_sh(sums2[c + 1], sums2[128 + c + 1], g2[c + 1], be2[c + 1], invN, scy, shy);
    }
    float sx = 0.f, sy = 0.f, s2x = 0.f, s2y = 0.f;
    for (int r = rbeg + rg; r < rend; r += 4) {
        float2 v = __half22float2(h[(size_t)r * 64 + cp]);
        if (TRANSFORM) {
            v.x = fmaxf(v.x * scx + shx, 0.f);
            v.y = fmaxf(v.y * scy + shy, 0.f);
        }
        sx += v.x; sy += v.y;
        s2x += v.x * v.x; s2y += v.y * v.y;
    }
    __shared__ float ls[4][256];
    ls[0][threadIdx.x] = sx;
    ls[1][threadIdx.x] = sy;
    ls[2][threadIdx.x] = s2x;
    ls[3][threadIdx.x] = s2y;
    __syncthreads();
    if (threadIdx.x < 64) {
        int t = threadIdx.x;
        float a0 = ls[0][t] + ls[0][t + 64] + ls[0][t + 128] + ls[0][t + 192];
        float a1 = ls[1][t] + ls[1][t + 64] + ls[1][t + 128] + ls[1][t + 192];
        float a2 = ls[2][t] + ls[2][t + 64] + ls[2][t + 128] + ls[2][t + 192];
        float a3 = ls[3][t] + ls[3][t + 64] + ls[3][t + 128] + ls[3][t + 192];
        atomicAdd(&stats[2 * t], a0);
        atomicAdd(&stats[2 * t + 1], a1);
        atomicAdd(&stats[128 + 2 * t], a2);
        atomicAdd(&stats[128 + 2 * t + 1], a3);
    }
}

// ---------------- head: bn3(relu(bn2(h)))@Wm + bm + log_softmax via MFMA ----------------
__global__ __launch_bounds__(256) void k_final(const __half* __restrict__ h,
                                               const float* __restrict__ sums2,
                                               const float* __restrict__ g2,
                                               const float* __restrict__ be2,
                                               const float* __restrict__ sums3,
                                               const float* __restrict__ g3,
                                               const float* __restrict__ be3, float invN,
                                               const unsigned short* __restrict__ packWm,
                                               const float* __restrict__ bm,
                                               float* __restrict__ out, int N) {
    int lane = threadIdx.x & 63;
    int wv = threadIdx.x >> 6;
    int m0 = (blockIdx.x * 4 + wv) * 16;
    if (m0 >= N) return;  // wave-uniform, no LDS/barrier
    int row = lane & 15, quad = lane >> 4;

    floatx4 acc[3];
#pragma unroll
    for (int nt = 0; nt < 3; ++nt) acc[nt] = (floatx4){0.f, 0.f, 0.f, 0.f};

    const __half* arow = h + (size_t)(m0 + row) * 128;
#pragma unroll
    for (int t = 0; t < 4; ++t) {
        int kbase = t * 32 + quad * 8;
        float av[8];
        load_row8(arow, kbase, av);
#pragma unroll
        for (int j = 0; j < 8; ++j) {
            int c = kbase + j;
            float sc2, sh2, sc3, sh3;
            bn_sc_sh(sums2[c], sums2[128 + c], g2[c], be2[c], invN, sc2, sh2);
            bn_sc_sh(sums3[c], sums3[128 + c], g3[c], be3[c], invN, sc3, sh3);
            av[j] = fmaxf(av[j] * sc2 + sh2, 0.f) * sc3 + sh3;
        }
        short8 ah, al;
#pragma unroll
        for (int j = 0; j < 8; ++j) {
            unsigned short hi = f2bf(av[j]);
            ah[j] = (short)hi;
            al[j] = (short)f2bf(av[j] - bf2f(hi));
        }
        const unsigned short* wp = packWm + (size_t)(t * 3) * 1024 + lane * 16;
#pragma unroll
        for (int nt = 0; nt < 3; ++nt) {
            short8 wh = *(const short8*)wp;
            short8 wl = *(const short8*)(wp + 8);
            wp += 1024;
            acc[nt] = __builtin_amdgcn_mfma_f32_16x16x32_bf16(ah, wh, acc[nt], 0, 0, 0);
            acc[nt] = __builtin_amdgcn_mfma_f32_16x16x32_bf16(al, wh, acc[nt], 0, 0, 0);
            acc[nt] = __builtin_amdgcn_mfma_f32_16x16x32_bf16(ah, wl, acc[nt], 0, 0, 0);
        }
    }

    float bb[3];
#pragma unroll
    for (int nt = 0; nt < 3; ++nt) {
        int col = nt * 16 + row;
        bb[nt] = (col < 40) ? bm[col] : 0.f;
    }
    bool val2 = (row < 8);  // nt=2 cols 32..47 valid iff col<40

#pragma unroll
    for (int r = 0; r < 4; ++r) {
        int m = m0 + quad * 4 + r;
        float v0 = acc[0][r] + bb[0];
        float v1 = acc[1][r] + bb[1];
        float v2 = acc[2][r] + bb[2];
        float mx = fmaxf(v0, v1);
        if (val2) mx = fmaxf(mx, v2);
#pragma unroll
        for (int off = 1; off <= 8; off <<= 1) mx = fmaxf(mx, __shfl_xor(mx, off, 64));
        float s = expf(v0 - mx) + expf(v1 - mx) + (val2 ? expf(v2 - mx) : 0.f);
#pragma unroll
        for (int off = 1; off <= 8; off <<= 1) s += __shfl_xor(s, off, 64);
        float lse = mx + logf(s);
        if (m < N) {
            out[(size_t)m * 40 + row] = v0 - lse;
            out[(size_t)m * 40 + 16 + row] = v1 - lse;
            if (val2) out[(size_t)m * 40 + 32 + row] = v2 - lse;
        }
    }
}

// ---------------- launcher ----------------
extern "C" void kernel_launch(void* const* d_in, const int* in_sizes, int n_in,
                              void* d_out, int out_size, void* d_ws, size_t ws_size,
                              hipStream_t stream) {
    const float* x   = (const float*)d_in[0];
    const int*   ei  = (const int*)d_in[1];
    const float* W1  = (const float*)d_in[2];
    const float* b1  = (const float*)d_in[3];
    const float* W2  = (const float*)d_in[4];
    const float* b2  = (const float*)d_in[5];
    const float* g1  = (const float*)d_in[6];
    const float* be1 = (const float*)d_in[7];
    const float* g2  = (const float*)d_in[8];
    const float* be2 = (const float*)d_in[9];
    const float* g3  = (const float*)d_in[10];
    const float* be3 = (const float*)d_in[11];
    const float* Wm  = (const float*)d_in[12];
    const float* bm  = (const float*)d_in[13];
    float* out = (float*)d_out;

    int N = in_sizes[0] / 128;
    int E = in_sizes[1] / 2;
    const int* srcs = ei;
    const int* dsts = ei + E;
    float invN = 1.0f / (float)N;

    char* ws = (char*)d_ws;
    size_t off = 0;
    auto alloc = [&](size_t bytes) -> void* {
        void* p = ws + off;
        off += (bytes + 255) & ~(size_t)255;
        return p;
    };
    // fillc and statsAll contiguous -> single zero pass in k_pre
    size_t fill_rounded = (((size_t)N * 4) + 255) & ~(size_t)255;
    int*   fillc   = (int*)alloc((size_t)N * 4);
    float* statsAll= (float*)alloc(3 * 256 * 4);  // stats1|stats2|stats3 raw sums
    float* stats1  = statsAll;
    float* stats2  = statsAll + 256;
    float* stats3  = statsAll + 512;
    unsigned short* col16 = (unsigned short*)alloc((size_t)N * CAP * 2);
    unsigned short* packW1 = (unsigned short*)alloc(32768 * 2);
    unsigned short* packW2 = (unsigned short*)alloc(32768 * 2);
    unsigned short* packWm = (unsigned short*)alloc(12288 * 2);
    __half* y16 = (__half*)alloc((size_t)N * 128 * 2);  // fp16 message buffer (reused)
    __half* h16 = (__half*)alloc((size_t)N * 128 * 2);  // fp16 hidden buffer
    (void)ws_size; (void)n_in; (void)out_size;

    int nthb = (N + 255) / 256;
    int gatherb = (N + 3) / 4;
    int gfb = (N + 63) / 64;          // k_final blocks (16 rows/wave)
    int ngemm = (N + 127) / 128;      // gemm blocks (32 rows/wave, 4 waves)
    const int NFILL = 1024;           // fill blocks (multiple of 8 for XCD shards)

    // zero region = fillc (rounded) + 3*256 floats, both 256-aligned -> int4 count
    int nz4 = (int)((fill_rounded + 3 * 256 * 4) / 16);
    int zb = (nz4 + 255) / 256;

    // pack weights + zero fillc/stats in one dispatch
    k_pre<<<19 + zb, 256, 0, stream>>>(W1, W2, Wm, packW1, packW2, packWm,
                                       (int4*)fillc, nz4);

    // layer-1 GEMM (no dinv dependency) overlapped with XCD-sharded CSR fill
    k_fill_gemm1<<<ngemm + NFILL, 256, 0, stream>>>(x, packW1, y16, N, ngemm, srcs, dsts, E,
                                                    fillc, col16, NFILL);

    // h = gather(y1 with dinv on both sides) + b1 ; stats1 (raw sums)
    k_gather<<<gatherb, 256, 0, stream>>>((const __half2*)y16, fillc, col16, b1,
                                          (__half2*)h16, N);
    k_stats<false><<<nthb, 256, 0, stream>>>((const __half2*)h16, N, nullptr, nullptr, nullptr,
                                             invN, stats1);

    // layer 2: y2 = fp16(relu(bn1(h))@W2) ; h = gather(y2)+b2 ; stats2
    k_gemm<__half, true><<<ngemm, 256, 0, stream>>>(h16, packW2, stats1, g1, be1, invN,
                                                    y16, N);
    k_gather<<<gatherb, 256, 0, stream>>>((const __half2*)y16, fillc, col16, b2,
                                          (__half2*)h16, N);
    k_stats<false><<<nthb, 256, 0, stream>>>((const __half2*)h16, N, nullptr, nullptr, nullptr,
                                             invN, stats2);

    // stats3 over relu(bn2(h)) (read-only); head applies bn3(relu(bn2(.))) composed
    k_stats<true><<<nthb, 256, 0, stream>>>((const __half2*)h16, N, stats2, g2, be2, invN,
                                            stats3);
    k_final<<<gfb, 256, 0, stream>>>(h16, stats2, g2, be2, stats3, g3, be3, invN, packWm, bm,
                                     out, N);
}